// Round 1
// baseline (6994.321 us; speedup 1.0000x reference)
//
#include <hip/hip_runtime.h>
#include <hip/hip_bf16.h>
#include <cstdint>
#include <cstddef>

#define Bb 256
#define Tt 512
#define Dd 256
#define Uu 256
#define NJ 768  // 3*U

// ---------------------------------------------------------------- utilities
__global__ void zero_len_kernel(int* __restrict__ len) {
    if (threadIdx.x < Bb) len[threadIdx.x] = 0;
}

// one wave per (b,t) row; 4 rows per 256-thread block; grid = B*T/4
__global__ void mask_len_kernel(const float* __restrict__ codes,
                                unsigned char* __restrict__ mask,
                                int* __restrict__ len) {
    const int wave = threadIdx.x >> 6;
    const int lane = threadIdx.x & 63;
    const long long row = (long long)blockIdx.x * 4 + wave;  // b*T + t
    const float4* p = reinterpret_cast<const float4*>(codes + row * Dd);
    float4 v = p[lane];  // 64 lanes * 4 floats = 256 = D
    bool nz = (v.x != 0.f) || (v.y != 0.f) || (v.z != 0.f) || (v.w != 0.f);
    unsigned long long ball = __ballot(nz);
    if (lane == 0) {
        int b = (int)(row >> 9);   // /512
        int t = (int)(row & 511);
        unsigned char m = (ball != 0ull) ? 1 : 0;
        mask[row] = m;
        if (m) atomicMax(&len[b], t + 1);
    }
}

// ------------------------------------------------- phase 1: mat_x = codes@W + b0
// 128x128 tile, 256 threads, 8x8 per thread, K=256 in 16-wide k-tiles.
// matx laid out [B][CT][768]; row r = b*CT + ct; codes row = b*T + t0 + ct.
__global__ __launch_bounds__(256)
void matx_gemm_kernel(const float* __restrict__ codes,
                      const float* __restrict__ W,
                      const float* __restrict__ b0,
                      float* __restrict__ matx,
                      int t0, int ctShift) {
    __shared__ float As[16][132];   // k-major, padded (+4) to break store conflicts
    __shared__ float Bs[16][128];
    const int tid = threadIdx.x;
    const int tx = tid & 15, ty = tid >> 4;
    const int rbase = blockIdx.x * 128;
    const int cbase = blockIdx.y * 128;
    const int ctMask = (1 << ctShift) - 1;

    float acc[8][8];
#pragma unroll
    for (int i = 0; i < 8; ++i)
#pragma unroll
        for (int j = 0; j < 8; ++j) acc[i][j] = 0.f;

    for (int kt = 0; kt < 16; ++kt) {
        const int k0 = kt * 16;
        float4 av[2], bv[2];
#pragma unroll
        for (int q = 0; q < 2; ++q) {
            int L = tid + q * 256;
            int arow = L >> 2, kq = (L & 3) * 4;
            int r = rbase + arow;
            int b = r >> ctShift, ct = r & ctMask;
            size_t aoff = ((size_t)b * Tt + (size_t)(t0 + ct)) * Dd + (k0 + kq);
            av[q] = *reinterpret_cast<const float4*>(codes + aoff);
            int brow = L >> 5, c4 = (L & 31) * 4;
            bv[q] = *reinterpret_cast<const float4*>(W + (size_t)(k0 + brow) * NJ + cbase + c4);
        }
        __syncthreads();
#pragma unroll
        for (int q = 0; q < 2; ++q) {
            int L = tid + q * 256;
            int arow = L >> 2, kq = (L & 3) * 4;
            As[kq + 0][arow] = av[q].x;
            As[kq + 1][arow] = av[q].y;
            As[kq + 2][arow] = av[q].z;
            As[kq + 3][arow] = av[q].w;
            int brow = L >> 5, c4 = (L & 31) * 4;
            *reinterpret_cast<float4*>(&Bs[brow][c4]) = bv[q];
        }
        __syncthreads();
#pragma unroll
        for (int k = 0; k < 16; ++k) {
            float4 a0 = *reinterpret_cast<const float4*>(&As[k][ty * 4]);
            float4 a1 = *reinterpret_cast<const float4*>(&As[k][64 + ty * 4]);
            float4 c0 = *reinterpret_cast<const float4*>(&Bs[k][tx * 4]);
            float4 c1 = *reinterpret_cast<const float4*>(&Bs[k][64 + tx * 4]);
            float ar[8] = {a0.x, a0.y, a0.z, a0.w, a1.x, a1.y, a1.z, a1.w};
            float bc[8] = {c0.x, c0.y, c0.z, c0.w, c1.x, c1.y, c1.z, c1.w};
#pragma unroll
            for (int i = 0; i < 8; ++i)
#pragma unroll
                for (int j = 0; j < 8; ++j) acc[i][j] += ar[i] * bc[j];
        }
        __syncthreads();
    }
    float4 bias0 = *reinterpret_cast<const float4*>(b0 + cbase + tx * 4);
    float4 bias1 = *reinterpret_cast<const float4*>(b0 + cbase + 64 + tx * 4);
#pragma unroll
    for (int i = 0; i < 8; ++i) {
        int r = rbase + ((i < 4) ? (ty * 4 + i) : (64 + ty * 4 + (i - 4)));
        float* mp = matx + (size_t)r * NJ + cbase;
        float4 s0 = make_float4(acc[i][0] + bias0.x, acc[i][1] + bias0.y,
                                acc[i][2] + bias0.z, acc[i][3] + bias0.w);
        float4 s1 = make_float4(acc[i][4] + bias1.x, acc[i][5] + bias1.y,
                                acc[i][6] + bias1.z, acc[i][7] + bias1.w);
        *reinterpret_cast<float4*>(mp + tx * 4) = s0;
        *reinterpret_cast<float4*>(mp + 64 + tx * 4) = s1;
    }
}

// ------------------------------------------------- phase 2: sequential GRU scan
// One block per 2 batch rows (128 blocks). Thread i owns gate columns
// {i, i+256, i+512}; h double-buffered in LDS (broadcast reads), 1 barrier/step.
__device__ __forceinline__ float sigmoidf_(float x) { return 1.f / (1.f + expf(-x)); }

__global__ __launch_bounds__(256)
void gru_scan_kernel(const float* __restrict__ matx,
                     const float* __restrict__ Uk,
                     const float* __restrict__ bias1,
                     const unsigned char* __restrict__ mask,
                     const int* __restrict__ len,
                     float* __restrict__ hws,
                     float* __restrict__ out,
                     int t0, int CT, int last) {
    __shared__ float hsm[2][2][Uu];
    const int i = threadIdx.x;           // 0..255 = gate column
    const int r0 = blockIdx.x * 2;       // batch rows r0, r0+1
    const int r1 = r0 + 1;
    const float bz = bias1[i], br = bias1[i + 256], bh = bias1[i + 512];

    float h0, h1;
    if (t0 == 0) { h0 = 0.f; h1 = 0.f; }
    else { h0 = hws[(size_t)r0 * Uu + i]; h1 = hws[(size_t)r1 * Uu + i]; }
    hsm[0][0][i] = h0; hsm[0][1][i] = h1;
    const int tend = min(t0 + CT, max(len[r0], len[r1]));
    __syncthreads();

    const float* __restrict__ uzp = Uk + i;
    const float* __restrict__ urp = Uk + i + 256;
    const float* __restrict__ uhp = Uk + i + 512;
    int p = 0;
    for (int t = t0; t < tend; ++t) {
        const int tl = t - t0;
        const float* hp0 = hsm[p][0];
        const float* hp1 = hsm[p][1];
        float az0 = bz, ar0 = br, ah0 = bh;
        float az1 = bz, ar1 = br, ah1 = bh;
#pragma unroll 2
        for (int k = 0; k < 256; k += 4) {
            float4 ha = *reinterpret_cast<const float4*>(hp0 + k);
            float4 hb = *reinterpret_cast<const float4*>(hp1 + k);
            float ha4[4] = {ha.x, ha.y, ha.z, ha.w};
            float hb4[4] = {hb.x, hb.y, hb.z, hb.w};
#pragma unroll
            for (int j = 0; j < 4; ++j) {
                const size_t o = (size_t)(k + j) * NJ;
                float uz = uzp[o], ur = urp[o], uh = uhp[o];
                az0 += ha4[j] * uz; ar0 += ha4[j] * ur; ah0 += ha4[j] * uh;
                az1 += hb4[j] * uz; ar1 += hb4[j] * ur; ah1 += hb4[j] * uh;
            }
        }
        const unsigned char m0 = mask[(size_t)r0 * Tt + t];
        const unsigned char m1 = mask[(size_t)r1 * Tt + t];
        const float* mr0 = matx + ((size_t)r0 * CT + tl) * NJ;
        const float* mr1 = matx + ((size_t)r1 * CT + tl) * NJ;
        if (m0) {
            float z = sigmoidf_(mr0[i] + az0);
            float r = sigmoidf_(mr0[i + 256] + ar0);
            float hc = tanhf(mr0[i + 512] + r * ah0);
            h0 = z * h0 + (1.f - z) * hc;
        }
        if (m1) {
            float z = sigmoidf_(mr1[i] + az1);
            float r = sigmoidf_(mr1[i + 256] + ar1);
            float hc = tanhf(mr1[i + 512] + r * ah1);
            h1 = z * h1 + (1.f - z) * hc;
        }
        p ^= 1;
        hsm[p][0][i] = h0;
        hsm[p][1][i] = h1;
        __syncthreads();
    }
    hws[(size_t)r0 * Uu + i] = h0;
    hws[(size_t)r1 * Uu + i] = h1;
    if (last) {
        out[(size_t)r0 * Uu + i] = h0;
        out[(size_t)r1 * Uu + i] = h1;
    }
}

// ---------------------------------------------------------------- launcher
extern "C" void kernel_launch(void* const* d_in, const int* in_sizes, int n_in,
                              void* d_out, int out_size, void* d_ws, size_t ws_size,
                              hipStream_t stream) {
    const float* codes = (const float*)d_in[0];
    const float* W     = (const float*)d_in[1];
    const float* Uk    = (const float*)d_in[2];
    const float* bias  = (const float*)d_in[3];   // [2][768]
    float* out = (float*)d_out;

    // ws layout: hws [B][256] f32 | len [B] i32 | mask [B][T] u8 | matx [B][CT][768] f32
    char* ws = (char*)d_ws;
    float* hws = (float*)ws;                              // 262144 B
    int* len = (int*)(ws + 262144);                       // 1024 B (pad to 263168)
    unsigned char* mask = (unsigned char*)(ws + 263168);  // 131072 B -> 394240
    float* matx = (float*)(ws + 394240);

    // largest power-of-two time-chunk that fits in ws (pure function of ws_size)
    int CT = 1;
    for (int c = 512; c >= 1; c >>= 1) {
        if (394240ull + (size_t)c * 786432ull <= ws_size) { CT = c; break; }
    }
    int ctShift = __builtin_ctz((unsigned)CT);
    int nch = 512 / CT;

    zero_len_kernel<<<1, 256, 0, stream>>>(len);
    mask_len_kernel<<<Bb * Tt / 4, 256, 0, stream>>>(codes, mask, len);

    for (int c = 0; c < nch; ++c) {
        int t0 = c * CT;
        dim3 grid(2 * CT, 6);  // (B*CT/128, 768/128)
        matx_gemm_kernel<<<grid, 256, 0, stream>>>(codes, W, bias, matx, t0, ctShift);
        gru_scan_kernel<<<128, 256, 0, stream>>>(matx, Uk, bias + NJ, mask, len,
                                                 hws, out, t0, CT, (c == nch - 1) ? 1 : 0);
    }
}